// Round 7
// baseline (246.324 us; speedup 1.0000x reference)
//
#include <hip/hip_runtime.h>

#define N_NODES 50000
#define N_EDGES 800000
#define IN_F 256
#define OUT_F 128
#define NWORDS (N_NODES / 4)     // 12500 packed node-words (int4 granularity)

#define GEMMF_BLOCKS 196         // 256 rows each -> 50176 >= 50000
#define HISTB 391                // 2048 edges each -> 800768 >= 800000
#define SCAT_BLOCKS 782          // 1024 edges each
#define ZERO_BLOCKS 13           // 13*1024 = 13312 >= 12500 int4 words

typedef __attribute__((ext_vector_type(8))) short short8;
typedef __attribute__((ext_vector_type(4))) float float4_t;

// float -> bf16 round-to-nearest-even
__device__ __forceinline__ short f2bf(float f) {
  unsigned u = __builtin_bit_cast(unsigned, f);
  u = u + 0x7FFFu + ((u >> 16) & 1u);
  return (short)(u >> 16);
}

__device__ __forceinline__ float bflo(unsigned u) {
  return __builtin_bit_cast(float, u << 16);
}
__device__ __forceinline__ float bfhi(unsigned u) {
  return __builtin_bit_cast(float, u & 0xFFFF0000u);
}

// ---- K0: zero the atomic counters (workspace is poisoned between runs) ----
__global__ __launch_bounds__(1024) void zero_kernel(int* __restrict__ dstcnt,
                                                    int* __restrict__ srccnt,
                                                    int* __restrict__ cursor) {
  int i = blockIdx.x * 1024 + threadIdx.x;
  if (i == 0) *cursor = 0;
  if (i < NWORDS) {
    ((int4*)dstcnt)[i] = (int4){0, 0, 0, 0};
    ((int4*)srccnt)[i] = (int4){0, 0, 0, 0};
  }
}

// ---- K1: fused GEMM + global-atomic histograms ----
// blocks [0,196): h = feat @ W (bf16 MFMA, W staged to LDS, norm deferred to agg)
// blocks [196,587): degree histograms via direct global atomicAdd (order-free;
// replaces the whole 128-chunk LDS-table machinery: ~75 MB of table traffic gone).
// Hist atomics hide under the longer GEMM blocks.
__global__ __launch_bounds__(512) void fused1_kernel(const int* __restrict__ src,
                                                     const int* __restrict__ dst,
                                                     int* __restrict__ dstcnt,
                                                     int* __restrict__ srccnt,
                                                     const float* __restrict__ W,
                                                     const float* __restrict__ feat,
                                                     unsigned short* __restrict__ h) {
  __shared__ uint4 smem4[4096];  // 64 KB W-bf16 (GEMM blocks only)
  int b = blockIdx.x;
  int tid = threadIdx.x;

  if (b < GEMMF_BLOCKS) {
    // ---- GEMM path (verified R5 structure) ----
    short* wl = (short*)smem4;
#pragma unroll
    for (int i = 0; i < 64; ++i) {
      int idx = i * 512 + tid;
      int k = idx >> 7, n = idx & 127;
      int s = k >> 5, q = (k >> 3) & 3, j = k & 7;
      int tt = n >> 4, m = n & 15;
      wl[((s * 8 + tt) * 64 + q * 16 + m) * 8 + j] = f2bf(W[idx]);
    }
    __syncthreads();

    int w = tid >> 6, l = tid & 63;
    int m = l & 15, q = l >> 4;
    long base = (long)b * 256 + w * 32;

    float4_t acc[2][8];
#pragma unroll
    for (int r = 0; r < 2; ++r)
#pragma unroll
      for (int to = 0; to < 8; ++to) acc[r][to] = (float4_t)(0.0f);

    long row0 = base + m;
    long row1 = base + 16 + m;
    long r0c = row0 < N_NODES - 1 ? row0 : N_NODES - 1;
    long r1c = row1 < N_NODES - 1 ? row1 : N_NODES - 1;
    const float* a0p = feat + (size_t)r0c * IN_F;
    const float* a1p = feat + (size_t)r1c * IN_F;
    const short8* wl8 = (const short8*)smem4;

#pragma unroll
    for (int s = 0; s < 8; ++s) {
      int k0 = s * 32 + q * 8;
      float4_t av0a = *(const float4_t*)(a0p + k0);
      float4_t av0b = *(const float4_t*)(a0p + k0 + 4);
      float4_t av1a = *(const float4_t*)(a1p + k0);
      float4_t av1b = *(const float4_t*)(a1p + k0 + 4);
      short8 fa0, fa1;
#pragma unroll
      for (int i = 0; i < 4; ++i) {
        fa0[i] = f2bf(av0a[i]);
        fa0[i + 4] = f2bf(av0b[i]);
        fa1[i] = f2bf(av1a[i]);
        fa1[i + 4] = f2bf(av1b[i]);
      }
#pragma unroll
      for (int to = 0; to < 8; ++to) {
        short8 fb = wl8[(s * 8 + to) * 64 + l];
        acc[0][to] = __builtin_amdgcn_mfma_f32_16x16x32_bf16(fa0, fb, acc[0][to], 0, 0, 0);
        acc[1][to] = __builtin_amdgcn_mfma_f32_16x16x32_bf16(fa1, fb, acc[1][to], 0, 0, 0);
      }
    }

    // C/D layout: col = lane&15 (=m), row = q*4 + i
#pragma unroll
    for (int r = 0; r < 2; ++r) {
#pragma unroll
      for (int i = 0; i < 4; ++i) {
        long row = base + r * 16 + q * 4 + i;
        if (row < N_NODES) {
          size_t ho = (size_t)row * OUT_F;
#pragma unroll
          for (int to = 0; to < 8; ++to) {
            h[ho + to * 16 + m] = (unsigned short)f2bf(acc[r][to][i]);
          }
        }
      }
    }
    return;
  }

  // ---- hist path: 4 edges/thread, direct global atomics ----
  int hb = b - GEMMF_BLOCKS;
  int e = hb * 2048 + tid * 4;
  if (e >= N_EDGES) return;
  int4 d4 = *(const int4*)(dst + e);
  int4 s4 = *(const int4*)(src + e);
  atomicAdd(&dstcnt[d4.x], 1);
  atomicAdd(&dstcnt[d4.y], 1);
  atomicAdd(&dstcnt[d4.z], 1);
  atomicAdd(&dstcnt[d4.w], 1);
  atomicAdd(&srccnt[s4.x], 1);
  atomicAdd(&srccnt[s4.y], 1);
  atomicAdd(&srccnt[s4.z], 1);
  atomicAdd(&srccnt[s4.w], 1);
}

// ---- K2: segment allocation (unordered prefix via cursor atomic) + norm ----
// row_start[d] need not be monotonic in d — it is just a disjoint allocation of
// [0, N_EDGES) into segments of size dstcnt[d]. Wave-scan + one atomicAdd(cursor)
// per wave. Also writes cur[] (scatter cursors) and norm[] from srccnt.
// grid 49 x 256: 196 waves x 64 lanes x int4 = 50176 >= 50000 nodes.
__global__ __launch_bounds__(256) void alloc_kernel(const int* __restrict__ dstcnt,
                                                    const int* __restrict__ srccnt,
                                                    int* __restrict__ row_start,
                                                    int* __restrict__ cur,
                                                    float* __restrict__ norm,
                                                    int* __restrict__ cursor) {
  int tid = threadIdx.x;
  int w = tid >> 6, l = tid & 63;
  int wd = (blockIdx.x * 4 + w) * 64 + l;  // int4 word index
  bool ok = wd < NWORDS;
  int4 c4 = ok ? ((const int4*)dstcnt)[wd] : (int4){0, 0, 0, 0};
  int T = c4.x + c4.y + c4.z + c4.w;
  int x = T;
#pragma unroll
  for (int off = 1; off < 64; off <<= 1) {
    int y = __shfl_up(x, off);
    if (l >= off) x += y;
  }
  int waveTotal = __shfl(x, 63);
  int sb = 0;
  if (l == 63) sb = atomicAdd(cursor, waveTotal);
  sb = __shfl(sb, 63);
  int E = sb + x - T;
  if (ok) {
    int4 rv = {E, E + c4.x, E + c4.x + c4.y, E + c4.x + c4.y + c4.z};
    ((int4*)row_start)[wd] = rv;
    ((int4*)cur)[wd] = rv;
    int4 s4v = ((const int4*)srccnt)[wd];
    float4 nv;
    nv.x = 1.0f / (float)(s4v.x > 1 ? s4v.x : 1);
    nv.y = 1.0f / (float)(s4v.y > 1 ? s4v.y : 1);
    nv.z = 1.0f / (float)(s4v.z > 1 ? s4v.z : 1);
    nv.w = 1.0f / (float)(s4v.w > 1 ? s4v.w : 1);
    ((float4*)norm)[wd] = nv;
  }
}

// ---- K3: scatter via per-node cursor atomics (order-free position alloc) ----
__global__ __launch_bounds__(256) void scat_kernel(const int* __restrict__ src,
                                                   const int* __restrict__ dst,
                                                   int* __restrict__ cur,
                                                   int* __restrict__ eidx) {
  int e = (blockIdx.x * 256 + threadIdx.x) * 4;
  if (e >= N_EDGES) return;
  int4 d4 = *(const int4*)(dst + e);
  int4 s4 = *(const int4*)(src + e);
  int dd[4] = {d4.x, d4.y, d4.z, d4.w};
  int ss[4] = {s4.x, s4.y, s4.z, s4.w};
#pragma unroll
  for (int k = 0; k < 4; ++k) {
    int pos = atomicAdd(&cur[dd[k]], 1);
    eidx[pos] = ss[k];
  }
}

// ---- agg: reverted to the R5-verified full-row gather (35 us, cache-BW floor) ----
// One wave per dst node; norm applied per gathered row (fma).
__global__ __launch_bounds__(256) void agg_kernel(const unsigned short* __restrict__ h,
                                                  const int* __restrict__ row_start,
                                                  const int* __restrict__ cnt,
                                                  const int* __restrict__ eidx,
                                                  const float* __restrict__ norm,
                                                  const float* __restrict__ bias,
                                                  float* __restrict__ out) {
  int w = threadIdx.x >> 6, l = threadIdx.x & 63;
  int d = blockIdx.x * 4 + w;  // grid 12500 -> exactly 50000
  int rs = row_start[d], re = rs + cnt[d];
  const unsigned* __restrict__ hu = (const unsigned*)h;  // 64 uints per row
  int rowsel = l >> 5, cp = l & 31;  // lane covers cols 4*cp .. 4*cp+3
  float a0 = 0.f, a1 = 0.f, a2 = 0.f, a3 = 0.f;
  for (int bse = rs; bse < re; bse += 64) {
    int n = re - bse; if (n > 64) n = 64;
    int e = (l < n) ? eidx[bse + l] : 0;
    int half = (n + 1) >> 1;
    int j = 0;
    for (; j + 4 <= half; j += 4) {  // 8 rows per iteration, 4 gathers in flight
      int i0 = 2 * j + rowsel;
      int s0 = __shfl(e, i0);
      int s1 = __shfl(e, i0 + 2);
      int s2 = __shfl(e, i0 + 4);
      int s3 = __shfl(e, i0 + 6);
      uint2 v0 = *(const uint2*)(hu + (size_t)s0 * 64 + 2 * cp);
      uint2 v1 = *(const uint2*)(hu + (size_t)s1 * 64 + 2 * cp);
      uint2 v2 = *(const uint2*)(hu + (size_t)s2 * 64 + 2 * cp);
      uint2 v3 = *(const uint2*)(hu + (size_t)s3 * 64 + 2 * cp);
      float nm0 = norm[s0], nm1 = norm[s1], nm2 = norm[s2], nm3 = norm[s3];
      if (i0 >= n) { v0.x = 0; v0.y = 0; }
      if (i0 + 2 >= n) { v1.x = 0; v1.y = 0; }
      if (i0 + 4 >= n) { v2.x = 0; v2.y = 0; }
      if (i0 + 6 >= n) { v3.x = 0; v3.y = 0; }
      a0 = fmaf(bflo(v0.x), nm0, a0); a1 = fmaf(bfhi(v0.x), nm0, a1);
      a2 = fmaf(bflo(v0.y), nm0, a2); a3 = fmaf(bfhi(v0.y), nm0, a3);
      a0 = fmaf(bflo(v1.x), nm1, a0); a1 = fmaf(bfhi(v1.x), nm1, a1);
      a2 = fmaf(bflo(v1.y), nm1, a2); a3 = fmaf(bfhi(v1.y), nm1, a3);
      a0 = fmaf(bflo(v2.x), nm2, a0); a1 = fmaf(bfhi(v2.x), nm2, a1);
      a2 = fmaf(bflo(v2.y), nm2, a2); a3 = fmaf(bfhi(v2.y), nm2, a3);
      a0 = fmaf(bflo(v3.x), nm3, a0); a1 = fmaf(bfhi(v3.x), nm3, a1);
      a2 = fmaf(bflo(v3.y), nm3, a2); a3 = fmaf(bfhi(v3.y), nm3, a3);
    }
    for (; j + 2 <= half; j += 2) {
      int i0 = 2 * j + rowsel;
      int i1 = i0 + 2;
      int s0 = __shfl(e, i0);
      int s1 = __shfl(e, i1);
      uint2 v0 = *(const uint2*)(hu + (size_t)s0 * 64 + 2 * cp);
      uint2 v1 = *(const uint2*)(hu + (size_t)s1 * 64 + 2 * cp);
      float nm0 = norm[s0], nm1 = norm[s1];
      if (i0 >= n) { v0.x = 0; v0.y = 0; }
      if (i1 >= n) { v1.x = 0; v1.y = 0; }
      a0 = fmaf(bflo(v0.x), nm0, a0); a1 = fmaf(bfhi(v0.x), nm0, a1);
      a2 = fmaf(bflo(v0.y), nm0, a2); a3 = fmaf(bfhi(v0.y), nm0, a3);
      a0 = fmaf(bflo(v1.x), nm1, a0); a1 = fmaf(bfhi(v1.x), nm1, a1);
      a2 = fmaf(bflo(v1.y), nm1, a2); a3 = fmaf(bfhi(v1.y), nm1, a3);
    }
    for (; j < half; ++j) {
      int i0 = 2 * j + rowsel;
      int s0 = __shfl(e, i0);
      uint2 v0 = *(const uint2*)(hu + (size_t)s0 * 64 + 2 * cp);
      float nm0 = norm[s0];
      if (i0 >= n) { v0.x = 0; v0.y = 0; }
      a0 = fmaf(bflo(v0.x), nm0, a0); a1 = fmaf(bfhi(v0.x), nm0, a1);
      a2 = fmaf(bflo(v0.y), nm0, a2); a3 = fmaf(bfhi(v0.y), nm0, a3);
    }
  }
  a0 += __shfl_xor(a0, 32);
  a1 += __shfl_xor(a1, 32);
  a2 += __shfl_xor(a2, 32);
  a3 += __shfl_xor(a3, 32);
  if (rowsel == 0) {
    float4 bv = ((const float4*)bias)[cp];
    float4 o;
    o.x = a0 + bv.x; o.y = a1 + bv.y; o.z = a2 + bv.z; o.w = a3 + bv.w;
    ((float4*)(out + (size_t)d * OUT_F))[cp] = o;
  }
}

extern "C" void kernel_launch(void* const* d_in, const int* in_sizes, int n_in,
                              void* d_out, int out_size, void* d_ws, size_t ws_size,
                              hipStream_t stream) {
  const float* feat = (const float*)d_in[0];
  const float* weight = (const float*)d_in[1];
  const float* bias = (const float*)d_in[2];
  const int* src = (const int*)d_in[3];
  const int* dst = (const int*)d_in[4];
  float* out = (float*)d_out;

  char* ws = (char*)d_ws;
  size_t off = 0;
  auto alloc = [&](size_t bytes) -> void* {
    void* p = ws + off;
    off += (bytes + 511) & ~(size_t)511;
    return p;
  };
  int* cursor = (int*)alloc(4);
  int* dstcnt = (int*)alloc(N_NODES * 4);
  int* srccnt = (int*)alloc(N_NODES * 4);
  int* row_start = (int*)alloc(N_NODES * 4);
  int* cur = (int*)alloc(N_NODES * 4);
  float* norm = (float*)alloc(N_NODES * 4);
  int* eidx = (int*)alloc(N_EDGES * 4);
  unsigned short* h = (unsigned short*)alloc((size_t)N_NODES * OUT_F * 2);
  (void)off; (void)ws_size; (void)in_sizes; (void)n_in; (void)out_size;

  hipLaunchKernelGGL(zero_kernel, dim3(ZERO_BLOCKS), dim3(1024), 0, stream,
                     dstcnt, srccnt, cursor);
  hipLaunchKernelGGL(fused1_kernel, dim3(GEMMF_BLOCKS + HISTB), dim3(512), 0, stream,
                     src, dst, dstcnt, srccnt, weight, feat, h);
  hipLaunchKernelGGL(alloc_kernel, dim3(49), dim3(256), 0, stream,
                     dstcnt, srccnt, row_start, cur, norm, cursor);
  hipLaunchKernelGGL(scat_kernel, dim3(SCAT_BLOCKS), dim3(256), 0, stream,
                     src, dst, cur, eidx);
  hipLaunchKernelGGL(agg_kernel, dim3(N_NODES / 4), dim3(256), 0, stream,
                     h, row_start, dstcnt, eidx, norm, bias, out);
}

// Round 8
// 178.981 us; speedup vs baseline: 1.3763x; 1.3763x over previous
//
#include <hip/hip_runtime.h>

#define N_NODES 50000
#define N_EDGES 800000
#define IN_F 256
#define OUT_F 128

#define CHUNKS 128
#define EPC (N_EDGES / CHUNKS)   // 6250 edges per chunk
#define BINW (N_NODES / 4)       // 12500 u32 words, 4 x u8 bins each (50 KB LDS)
#define NWORDS (N_NODES / 4)     // 12500 packed node-words
#define RGB 196                  // reduceoff blocks: 64 words (256 nodes) each
#define HIST_BLOCKS (2 * CHUNKS) // 256
#define CPW (CHUNKS / 4)         // 32 chunks per wave

#define GEMM_START HIST_BLOCKS   // gemm blocks start after hist blocks in K1
#define GEMMF_BLOCKS 196         // 256 rows each -> 50176 >= 50000
#define SCAT_BLOCKS 391          // 2048 edges each (8/thread) -> 800768 >= 800000

typedef __attribute__((ext_vector_type(8))) short short8;
typedef __attribute__((ext_vector_type(4))) float float4_t;

// float -> bf16 round-to-nearest-even
__device__ __forceinline__ short f2bf(float f) {
  unsigned u = __builtin_bit_cast(unsigned, f);
  u = u + 0x7FFFu + ((u >> 16) & 1u);
  return (short)(u >> 16);
}

__device__ __forceinline__ float bflo(unsigned u) {
  return __builtin_bit_cast(float, u << 16);
}
__device__ __forceinline__ float bfhi(unsigned u) {
  return __builtin_bit_cast(float, u & 0xFFFF0000u);
}

// ---- K1: fused dst-hist + src-hist + GEMM (norm deferred to agg) ----
// blocks [0,128): dst-side hist + per-edge rank; [128,256): src-side hist;
// blocks [256, 256+196): h = feat @ W (bf16 MFMA), W staged f32->bf16 into LDS
// per block. GEMM depends only on feat/W, so it runs concurrent with the
// hist critical path — its serial time vanishes.
// NOTE (R7 lesson): global-atomic histogram/scatter is 3-6x SLOWER than this
// chunked-table pipeline (cross-XCD hot-line atomics). Do not revisit.
__global__ __launch_bounds__(512) void fused1_kernel(const int* __restrict__ src,
                                                     const int* __restrict__ dst,
                                                     unsigned char* __restrict__ pdst8,
                                                     unsigned char* __restrict__ psrc8,
                                                     unsigned char* __restrict__ rank8,
                                                     const float* __restrict__ W,
                                                     const float* __restrict__ feat,
                                                     unsigned short* __restrict__ h,
                                                     int* __restrict__ cursor) {
  __shared__ uint4 smem4[4096];  // 64 KB: hist bins (50 KB) or W-bf16 (64 KB)
  int b = blockIdx.x;
  int tid = threadIdx.x;

  if (b >= GEMM_START) {
    // ---- GEMM path ----
    if (b == GEMM_START && tid == 0) *cursor = 0;  // consumed by reduceoff (next kernel)
    short* wl = (short*)smem4;
    // stage W: lane-ordered fragment layout -> contiguous 1KB per wave ds_read
#pragma unroll
    for (int i = 0; i < 64; ++i) {
      int idx = i * 512 + tid;
      int k = idx >> 7, n = idx & 127;
      int s = k >> 5, q = (k >> 3) & 3, j = k & 7;
      int tt = n >> 4, m = n & 15;
      wl[((s * 8 + tt) * 64 + q * 16 + m) * 8 + j] = f2bf(W[idx]);
    }
    __syncthreads();

    int w = tid >> 6, l = tid & 63;
    int m = l & 15, q = l >> 4;
    long base = (long)(b - GEMM_START) * 256 + w * 32;

    float4_t acc[2][8];
#pragma unroll
    for (int r = 0; r < 2; ++r)
#pragma unroll
      for (int to = 0; to < 8; ++to) acc[r][to] = (float4_t)(0.0f);

    long row0 = base + m;
    long row1 = base + 16 + m;
    long r0c = row0 < N_NODES - 1 ? row0 : N_NODES - 1;
    long r1c = row1 < N_NODES - 1 ? row1 : N_NODES - 1;
    const float* a0p = feat + (size_t)r0c * IN_F;
    const float* a1p = feat + (size_t)r1c * IN_F;
    const short8* wl8 = (const short8*)smem4;

#pragma unroll
    for (int s = 0; s < 8; ++s) {
      int k0 = s * 32 + q * 8;
      float4_t av0a = *(const float4_t*)(a0p + k0);
      float4_t av0b = *(const float4_t*)(a0p + k0 + 4);
      float4_t av1a = *(const float4_t*)(a1p + k0);
      float4_t av1b = *(const float4_t*)(a1p + k0 + 4);
      short8 fa0, fa1;
#pragma unroll
      for (int i = 0; i < 4; ++i) {
        fa0[i] = f2bf(av0a[i]);
        fa0[i + 4] = f2bf(av0b[i]);
        fa1[i] = f2bf(av1a[i]);
        fa1[i + 4] = f2bf(av1b[i]);
      }
#pragma unroll
      for (int to = 0; to < 8; ++to) {
        short8 fb = wl8[(s * 8 + to) * 64 + l];
        acc[0][to] = __builtin_amdgcn_mfma_f32_16x16x32_bf16(fa0, fb, acc[0][to], 0, 0, 0);
        acc[1][to] = __builtin_amdgcn_mfma_f32_16x16x32_bf16(fa1, fb, acc[1][to], 0, 0, 0);
      }
    }

    // C/D layout: col = lane&15 (=m), row = q*4 + i. No norm here (deferred to agg).
#pragma unroll
    for (int r = 0; r < 2; ++r) {
#pragma unroll
      for (int i = 0; i < 4; ++i) {
        long row = base + r * 16 + q * 4 + i;
        if (row < N_NODES) {
          size_t ho = (size_t)row * OUT_F;
#pragma unroll
          for (int to = 0; to < 8; ++to) {
            h[ho + to * 16 + m] = (unsigned short)f2bf(acc[r][to][i]);
          }
        }
      }
    }
    return;
  }

  // ---- hist path ----
  unsigned* bins = (unsigned*)smem4;
  int hs = b >> 7;
  int c = b & 127;
  uint4* b4 = (uint4*)bins;
  for (int j = tid; j < BINW / 4; j += 512) b4[j] = (uint4){0u, 0u, 0u, 0u};
  __syncthreads();
  const int* key = hs ? src : dst;
  int e0 = c * EPC;

  auto process = [&](int v, int eI) {
    unsigned sh = (v & 3) * 8;
    unsigned old = atomicAdd(&bins[v >> 2], 1u << sh);
    if (!hs) __builtin_nontemporal_store((unsigned char)((old >> sh) & 0xFFu), rank8 + eI);
  };

  // 3 full tiles of 2048 + tail of 106 (EPC = 6250)
#pragma unroll 2
  for (int tile = 0; tile < 3; ++tile) {
    int i = tile * 2048 + tid;
    int k0 = key[e0 + i];
    int k1 = key[e0 + i + 512];
    int k2 = key[e0 + i + 1024];
    int k3 = key[e0 + i + 1536];
    process(k0, e0 + i);
    process(k1, e0 + i + 512);
    process(k2, e0 + i + 1024);
    process(k3, e0 + i + 1536);
  }
  {
    int i = 6144 + tid;
    if (i < EPC) process(key[e0 + i], e0 + i);
  }
  __syncthreads();
  uint4* p128 = (uint4*)((hs ? psrc8 : pdst8) + (size_t)c * N_NODES);  // rows 16B-aligned
  const uint4* s128 = (const uint4*)bins;
  for (int j = tid; j < BINW / 4; j += 512) p128[j] = s128[j];
}

// grid (RGB, 2). Wave-split chunk prefix with packed-byte (4-node) arithmetic.
__global__ __launch_bounds__(256) void reduceoff_kernel(const unsigned char* __restrict__ pdst8,
                                                        const unsigned char* __restrict__ psrc8,
                                                        unsigned char* __restrict__ delta8,
                                                        int* __restrict__ cnt,
                                                        int* __restrict__ row_start,
                                                        int* __restrict__ cursor,
                                                        float* __restrict__ norm) {
  __shared__ unsigned tot[4][64];
  int g = blockIdx.x, side = blockIdx.y;
  int t = threadIdx.x;
  int w = t >> 6, l = t & 63;
  int wd = g * 64 + l;
  bool ok = wd < NWORDS;
  int wdc = ok ? wd : NWORDS - 1;  // clamp for safe addressing
  const unsigned* P = (const unsigned*)(side == 0 ? pdst8 : psrc8);

  unsigned vals[CPW];
  unsigned s = 0;
#pragma unroll
  for (int i = 0; i < CPW; ++i) {
    vals[i] = P[(size_t)(w * CPW + i) * NWORDS + wdc];
    s += vals[i];
  }
  tot[w][l] = s;
  __syncthreads();

  if (side == 0) {
    unsigned base = 0;
#pragma unroll
    for (int w2 = 0; w2 < 4; ++w2)
      if (w2 < w) base += tot[w2][l];
    unsigned run = base;
    unsigned* D = (unsigned*)delta8;
    if (ok) {
#pragma unroll
      for (int i = 0; i < CPW; ++i) {
        D[(size_t)(w * CPW + i) * NWORDS + wd] = run;
        run += vals[i];
      }
    }
    if (w == 0) {
      unsigned ftot = tot[0][l] + tot[1][l] + tot[2][l] + tot[3][l];
      if (!ok) ftot = 0;
      int c0 = ftot & 255, c1 = (ftot >> 8) & 255, c2 = (ftot >> 16) & 255, c3 = ftot >> 24;
      int T = c0 + c1 + c2 + c3;
      int x = T;
#pragma unroll
      for (int off = 1; off < 64; off <<= 1) {
        int y = __shfl_up(x, off);
        if (l >= off) x += y;
      }
      int waveTotal = __shfl(x, 63);
      int sb = 0;
      if (l == 63) sb = atomicAdd(cursor, waveTotal);
      sb = __shfl(sb, 63);
      int E = sb + x - T;
      if (ok) {
        int4 cv = {c0, c1, c2, c3};
        int4 rv = {E, E + c0, E + c0 + c1, E + c0 + c1 + c2};
        ((int4*)cnt)[wd] = cv;
        ((int4*)row_start)[wd] = rv;
      }
    }
  } else {
    if (w == 0 && ok) {
      unsigned ftot = tot[0][l] + tot[1][l] + tot[2][l] + tot[3][l];
      float4 nv;
      int d0 = ftot & 255, d1 = (ftot >> 8) & 255, d2 = (ftot >> 16) & 255, d3 = (int)(ftot >> 24);
      nv.x = 1.0f / (float)(d0 > 1 ? d0 : 1);
      nv.y = 1.0f / (float)(d1 > 1 ? d1 : 1);
      nv.z = 1.0f / (float)(d2 > 1 ? d2 : 1);
      nv.w = 1.0f / (float)(d3 > 1 ? d3 : 1);
      ((float4*)norm)[wd] = nv;
    }
  }
}

// ---- scatter: stateless, 8 edges/thread; nontemporal eidx stores to avoid
// cross-XCD L2 line ping-pong (each 64B eidx line has ~16 writers on different XCDs).
__global__ __launch_bounds__(256) void scat_kernel(const int* __restrict__ src,
                                                   const int* __restrict__ dst,
                                                   const int* __restrict__ row_start,
                                                   const unsigned char* __restrict__ delta8,
                                                   const unsigned char* __restrict__ rank8,
                                                   int* __restrict__ eidx) {
  int gt = blockIdx.x * 256 + threadIdx.x;
  int e = gt * 8;
  if (e >= N_EDGES) return;
  int4 d4a = *(const int4*)(dst + e);
  int4 d4b = *(const int4*)(dst + e + 4);
  int4 s4a = *(const int4*)(src + e);
  int4 s4b = *(const int4*)(src + e + 4);
  uint2 rr2 = *(const uint2*)(rank8 + e);
  int dd[8] = {d4a.x, d4a.y, d4a.z, d4a.w, d4b.x, d4b.y, d4b.z, d4b.w};
  int ss[8] = {s4a.x, s4a.y, s4a.z, s4a.w, s4b.x, s4b.y, s4b.z, s4b.w};
  unsigned rr[2] = {rr2.x, rr2.y};
#pragma unroll
  for (int k = 0; k < 8; ++k) {
    int c = (e + k) / EPC;
    int d = dd[k];
    int pos = row_start[d] + (int)delta8[(size_t)c * N_NODES + d] + (int)((rr[k >> 2] >> (8 * (k & 3))) & 0xFFu);
    __builtin_nontemporal_store(ss[k], eidx + pos);
  }
}

// One wave per dst node; norm applied here per gathered row (fma, norm[s] is a
// wave-broadcast load). This is what freed the GEMM from the reduceoff dependency.
__global__ __launch_bounds__(256) void agg_kernel(const unsigned short* __restrict__ h,
                                                  const int* __restrict__ row_start,
                                                  const int* __restrict__ cnt,
                                                  const int* __restrict__ eidx,
                                                  const float* __restrict__ norm,
                                                  const float* __restrict__ bias,
                                                  float* __restrict__ out) {
  int w = threadIdx.x >> 6, l = threadIdx.x & 63;
  int d = blockIdx.x * 4 + w;  // grid 12500 -> exactly 50000
  int rs = row_start[d], re = rs + cnt[d];
  const unsigned* __restrict__ hu = (const unsigned*)h;  // 64 uints per row
  int rowsel = l >> 5, cp = l & 31;  // lane covers cols 4*cp .. 4*cp+3
  float a0 = 0.f, a1 = 0.f, a2 = 0.f, a3 = 0.f;
  for (int bse = rs; bse < re; bse += 64) {
    int n = re - bse; if (n > 64) n = 64;
    int e = (l < n) ? eidx[bse + l] : 0;
    int half = (n + 1) >> 1;
    int j = 0;
    for (; j + 4 <= half; j += 4) {  // 8 rows per iteration, 4 gathers in flight
      int i0 = 2 * j + rowsel;
      int s0 = __shfl(e, i0);
      int s1 = __shfl(e, i0 + 2);
      int s2 = __shfl(e, i0 + 4);
      int s3 = __shfl(e, i0 + 6);
      uint2 v0 = *(const uint2*)(hu + (size_t)s0 * 64 + 2 * cp);
      uint2 v1 = *(const uint2*)(hu + (size_t)s1 * 64 + 2 * cp);
      uint2 v2 = *(const uint2*)(hu + (size_t)s2 * 64 + 2 * cp);
      uint2 v3 = *(const uint2*)(hu + (size_t)s3 * 64 + 2 * cp);
      float nm0 = norm[s0], nm1 = norm[s1], nm2 = norm[s2], nm3 = norm[s3];
      if (i0 >= n) { v0.x = 0; v0.y = 0; }
      if (i0 + 2 >= n) { v1.x = 0; v1.y = 0; }
      if (i0 + 4 >= n) { v2.x = 0; v2.y = 0; }
      if (i0 + 6 >= n) { v3.x = 0; v3.y = 0; }
      a0 = fmaf(bflo(v0.x), nm0, a0); a1 = fmaf(bfhi(v0.x), nm0, a1);
      a2 = fmaf(bflo(v0.y), nm0, a2); a3 = fmaf(bfhi(v0.y), nm0, a3);
      a0 = fmaf(bflo(v1.x), nm1, a0); a1 = fmaf(bfhi(v1.x), nm1, a1);
      a2 = fmaf(bflo(v1.y), nm1, a2); a3 = fmaf(bfhi(v1.y), nm1, a3);
      a0 = fmaf(bflo(v2.x), nm2, a0); a1 = fmaf(bfhi(v2.x), nm2, a1);
      a2 = fmaf(bflo(v2.y), nm2, a2); a3 = fmaf(bfhi(v2.y), nm2, a3);
      a0 = fmaf(bflo(v3.x), nm3, a0); a1 = fmaf(bfhi(v3.x), nm3, a1);
      a2 = fmaf(bflo(v3.y), nm3, a2); a3 = fmaf(bfhi(v3.y), nm3, a3);
    }
    for (; j + 2 <= half; j += 2) {
      int i0 = 2 * j + rowsel;
      int i1 = i0 + 2;
      int s0 = __shfl(e, i0);
      int s1 = __shfl(e, i1);
      uint2 v0 = *(const uint2*)(hu + (size_t)s0 * 64 + 2 * cp);
      uint2 v1 = *(const uint2*)(hu + (size_t)s1 * 64 + 2 * cp);
      float nm0 = norm[s0], nm1 = norm[s1];
      if (i0 >= n) { v0.x = 0; v0.y = 0; }
      if (i1 >= n) { v1.x = 0; v1.y = 0; }
      a0 = fmaf(bflo(v0.x), nm0, a0); a1 = fmaf(bfhi(v0.x), nm0, a1);
      a2 = fmaf(bflo(v0.y), nm0, a2); a3 = fmaf(bfhi(v0.y), nm0, a3);
      a0 = fmaf(bflo(v1.x), nm1, a0); a1 = fmaf(bfhi(v1.x), nm1, a1);
      a2 = fmaf(bflo(v1.y), nm1, a2); a3 = fmaf(bfhi(v1.y), nm1, a3);
    }
    for (; j < half; ++j) {
      int i0 = 2 * j + rowsel;
      int s0 = __shfl(e, i0);
      uint2 v0 = *(const uint2*)(hu + (size_t)s0 * 64 + 2 * cp);
      float nm0 = norm[s0];
      if (i0 >= n) { v0.x = 0; v0.y = 0; }
      a0 = fmaf(bflo(v0.x), nm0, a0); a1 = fmaf(bfhi(v0.x), nm0, a1);
      a2 = fmaf(bflo(v0.y), nm0, a2); a3 = fmaf(bfhi(v0.y), nm0, a3);
    }
  }
  a0 += __shfl_xor(a0, 32);
  a1 += __shfl_xor(a1, 32);
  a2 += __shfl_xor(a2, 32);
  a3 += __shfl_xor(a3, 32);
  if (rowsel == 0) {
    float4 bv = ((const float4*)bias)[cp];
    float4 o;
    o.x = a0 + bv.x; o.y = a1 + bv.y; o.z = a2 + bv.z; o.w = a3 + bv.w;
    ((float4*)(out + (size_t)d * OUT_F))[cp] = o;
  }
}

extern "C" void kernel_launch(void* const* d_in, const int* in_sizes, int n_in,
                              void* d_out, int out_size, void* d_ws, size_t ws_size,
                              hipStream_t stream) {
  const float* feat = (const float*)d_in[0];
  const float* weight = (const float*)d_in[1];
  const float* bias = (const float*)d_in[2];
  const int* src = (const int*)d_in[3];
  const int* dst = (const int*)d_in[4];
  float* out = (float*)d_out;

  char* ws = (char*)d_ws;
  size_t off = 0;
  auto alloc = [&](size_t bytes) -> void* {
    void* p = ws + off;
    off += (bytes + 511) & ~(size_t)511;
    return p;
  };
  int* cursor = (int*)alloc(4);
  int* cnt = (int*)alloc(N_NODES * 4);
  int* row_start = (int*)alloc(N_NODES * 4);
  float* norm = (float*)alloc(N_NODES * 4);
  int* eidx = (int*)alloc(N_EDGES * 4);
  unsigned short* h = (unsigned short*)alloc((size_t)N_NODES * OUT_F * 2);
  unsigned char* pdst8 = (unsigned char*)alloc((size_t)CHUNKS * N_NODES);
  unsigned char* psrc8 = (unsigned char*)alloc((size_t)CHUNKS * N_NODES);
  unsigned char* delta8 = (unsigned char*)alloc((size_t)CHUNKS * N_NODES);
  unsigned char* rank8 = (unsigned char*)alloc((size_t)N_EDGES);
  (void)off; (void)ws_size; (void)in_sizes; (void)n_in; (void)out_size;

  hipLaunchKernelGGL(fused1_kernel, dim3(HIST_BLOCKS + GEMMF_BLOCKS), dim3(512), 0, stream,
                     src, dst, pdst8, psrc8, rank8, weight, feat, h, cursor);
  hipLaunchKernelGGL(reduceoff_kernel, dim3(RGB, 2), dim3(256), 0, stream,
                     pdst8, psrc8, delta8, cnt, row_start, cursor, norm);
  hipLaunchKernelGGL(scat_kernel, dim3(SCAT_BLOCKS), dim3(256), 0, stream,
                     src, dst, row_start, delta8, rank8, eidx);
  hipLaunchKernelGGL(agg_kernel, dim3(N_NODES / 4), dim3(256), 0, stream,
                     h, row_start, cnt, eidx, norm, bias, out);
}

// Round 9
// 170.603 us; speedup vs baseline: 1.4438x; 1.0491x over previous
//
#include <hip/hip_runtime.h>

#define N_NODES 50000
#define N_EDGES 800000
#define IN_F 256
#define OUT_F 128

#define CHUNKS 128
#define EPC (N_EDGES / CHUNKS)   // 6250 edges per chunk
#define BINW (N_NODES / 4)       // 12500 u32 words, 4 x u8 bins each (50 KB LDS)
#define NWORDS (N_NODES / 4)     // 12500 packed node-words
#define RGB 196                  // reduceoff blocks: 64 words (256 nodes) each
#define HIST_BLOCKS (2 * CHUNKS) // 256
#define CPW (CHUNKS / 4)         // 32 chunks per wave

#define GEMM_START HIST_BLOCKS   // gemm blocks start after hist blocks in K1
#define GEMMF_BLOCKS 196         // 256 rows each -> 50176 >= 50000
#define SCAT_BLOCKS 782          // 1024 edges each (4/thread) -> 800768 >= 800000

typedef __attribute__((ext_vector_type(8))) short short8;
typedef __attribute__((ext_vector_type(4))) float float4_t;

// float -> bf16 round-to-nearest-even
__device__ __forceinline__ short f2bf(float f) {
  unsigned u = __builtin_bit_cast(unsigned, f);
  u = u + 0x7FFFu + ((u >> 16) & 1u);
  return (short)(u >> 16);
}

__device__ __forceinline__ float bflo(unsigned u) {
  return __builtin_bit_cast(float, u << 16);
}
__device__ __forceinline__ float bfhi(unsigned u) {
  return __builtin_bit_cast(float, u & 0xFFFF0000u);
}

// ---- K1: fused dst-hist + src-hist + GEMM (norm deferred to agg) ----
// blocks [0,128): dst-side hist + per-edge rank; [128,256): src-side hist;
// blocks [256, 256+196): h = feat @ W (bf16 MFMA), W staged f32->bf16 into LDS.
// R7 lesson: global-atomic hist/scatter is 3-6x SLOWER (cross-XCD hot lines).
// R8 lesson: nontemporal stores + 8 edges/thread scat regress ~8us. Keep plain.
__global__ __launch_bounds__(512) void fused1_kernel(const int* __restrict__ src,
                                                     const int* __restrict__ dst,
                                                     unsigned char* __restrict__ pdst8,
                                                     unsigned char* __restrict__ psrc8,
                                                     unsigned char* __restrict__ rank8,
                                                     const float* __restrict__ W,
                                                     const float* __restrict__ feat,
                                                     unsigned short* __restrict__ h,
                                                     int* __restrict__ cursor) {
  __shared__ uint4 smem4[4096];  // 64 KB: hist bins (50 KB) or W-bf16 (64 KB)
  int b = blockIdx.x;
  int tid = threadIdx.x;

  if (b >= GEMM_START) {
    // ---- GEMM path ----
    if (b == GEMM_START && tid == 0) *cursor = 0;  // consumed by reduceoff (next kernel)
    short* wl = (short*)smem4;
    // stage W: lane-ordered fragment layout -> contiguous 1KB per wave ds_read
#pragma unroll
    for (int i = 0; i < 64; ++i) {
      int idx = i * 512 + tid;
      int k = idx >> 7, n = idx & 127;
      int s = k >> 5, q = (k >> 3) & 3, j = k & 7;
      int tt = n >> 4, m = n & 15;
      wl[((s * 8 + tt) * 64 + q * 16 + m) * 8 + j] = f2bf(W[idx]);
    }
    __syncthreads();

    int w = tid >> 6, l = tid & 63;
    int m = l & 15, q = l >> 4;
    long base = (long)(b - GEMM_START) * 256 + w * 32;

    float4_t acc[2][8];
#pragma unroll
    for (int r = 0; r < 2; ++r)
#pragma unroll
      for (int to = 0; to < 8; ++to) acc[r][to] = (float4_t)(0.0f);

    long row0 = base + m;
    long row1 = base + 16 + m;
    long r0c = row0 < N_NODES - 1 ? row0 : N_NODES - 1;
    long r1c = row1 < N_NODES - 1 ? row1 : N_NODES - 1;
    const float* a0p = feat + (size_t)r0c * IN_F;
    const float* a1p = feat + (size_t)r1c * IN_F;
    const short8* wl8 = (const short8*)smem4;

#pragma unroll
    for (int s = 0; s < 8; ++s) {
      int k0 = s * 32 + q * 8;
      float4_t av0a = *(const float4_t*)(a0p + k0);
      float4_t av0b = *(const float4_t*)(a0p + k0 + 4);
      float4_t av1a = *(const float4_t*)(a1p + k0);
      float4_t av1b = *(const float4_t*)(a1p + k0 + 4);
      short8 fa0, fa1;
#pragma unroll
      for (int i = 0; i < 4; ++i) {
        fa0[i] = f2bf(av0a[i]);
        fa0[i + 4] = f2bf(av0b[i]);
        fa1[i] = f2bf(av1a[i]);
        fa1[i + 4] = f2bf(av1b[i]);
      }
#pragma unroll
      for (int to = 0; to < 8; ++to) {
        short8 fb = wl8[(s * 8 + to) * 64 + l];
        acc[0][to] = __builtin_amdgcn_mfma_f32_16x16x32_bf16(fa0, fb, acc[0][to], 0, 0, 0);
        acc[1][to] = __builtin_amdgcn_mfma_f32_16x16x32_bf16(fa1, fb, acc[1][to], 0, 0, 0);
      }
    }

    // C/D layout: col = lane&15 (=m), row = q*4 + i. No norm here (deferred to agg).
#pragma unroll
    for (int r = 0; r < 2; ++r) {
#pragma unroll
      for (int i = 0; i < 4; ++i) {
        long row = base + r * 16 + q * 4 + i;
        if (row < N_NODES) {
          size_t ho = (size_t)row * OUT_F;
#pragma unroll
          for (int to = 0; to < 8; ++to) {
            h[ho + to * 16 + m] = (unsigned short)f2bf(acc[r][to][i]);
          }
        }
      }
    }
    return;
  }

  // ---- hist path ----
  unsigned* bins = (unsigned*)smem4;
  int hs = b >> 7;
  int c = b & 127;
  uint4* b4 = (uint4*)bins;
  for (int j = tid; j < BINW / 4; j += 512) b4[j] = (uint4){0u, 0u, 0u, 0u};
  __syncthreads();
  const int* key = hs ? src : dst;
  int e0 = c * EPC;

  auto process = [&](int v, int eI) {
    unsigned sh = (v & 3) * 8;
    unsigned old = atomicAdd(&bins[v >> 2], 1u << sh);
    if (!hs) rank8[eI] = (unsigned char)((old >> sh) & 0xFFu);
  };

  // 3 full tiles of 2048 + tail of 106 (EPC = 6250)
#pragma unroll 2
  for (int tile = 0; tile < 3; ++tile) {
    int i = tile * 2048 + tid;
    int k0 = key[e0 + i];
    int k1 = key[e0 + i + 512];
    int k2 = key[e0 + i + 1024];
    int k3 = key[e0 + i + 1536];
    process(k0, e0 + i);
    process(k1, e0 + i + 512);
    process(k2, e0 + i + 1024);
    process(k3, e0 + i + 1536);
  }
  {
    int i = 6144 + tid;
    if (i < EPC) process(key[e0 + i], e0 + i);
  }
  __syncthreads();
  uint4* p128 = (uint4*)((hs ? psrc8 : pdst8) + (size_t)c * N_NODES);  // rows 16B-aligned
  const uint4* s128 = (const uint4*)bins;
  for (int j = tid; j < BINW / 4; j += 512) p128[j] = s128[j];
}

// grid (RGB, 2). Wave-split chunk prefix with packed-byte (4-node) arithmetic.
__global__ __launch_bounds__(256) void reduceoff_kernel(const unsigned char* __restrict__ pdst8,
                                                        const unsigned char* __restrict__ psrc8,
                                                        unsigned char* __restrict__ delta8,
                                                        int* __restrict__ cnt,
                                                        int* __restrict__ row_start,
                                                        int* __restrict__ cursor,
                                                        float* __restrict__ norm) {
  __shared__ unsigned tot[4][64];
  int g = blockIdx.x, side = blockIdx.y;
  int t = threadIdx.x;
  int w = t >> 6, l = t & 63;
  int wd = g * 64 + l;
  bool ok = wd < NWORDS;
  int wdc = ok ? wd : NWORDS - 1;  // clamp for safe addressing
  const unsigned* P = (const unsigned*)(side == 0 ? pdst8 : psrc8);

  unsigned vals[CPW];
  unsigned s = 0;
#pragma unroll
  for (int i = 0; i < CPW; ++i) {
    vals[i] = P[(size_t)(w * CPW + i) * NWORDS + wdc];
    s += vals[i];
  }
  tot[w][l] = s;
  __syncthreads();

  if (side == 0) {
    unsigned base = 0;
#pragma unroll
    for (int w2 = 0; w2 < 4; ++w2)
      if (w2 < w) base += tot[w2][l];
    unsigned run = base;
    unsigned* D = (unsigned*)delta8;
    if (ok) {
#pragma unroll
      for (int i = 0; i < CPW; ++i) {
        D[(size_t)(w * CPW + i) * NWORDS + wd] = run;
        run += vals[i];
      }
    }
    if (w == 0) {
      unsigned ftot = tot[0][l] + tot[1][l] + tot[2][l] + tot[3][l];
      if (!ok) ftot = 0;
      int c0 = ftot & 255, c1 = (ftot >> 8) & 255, c2 = (ftot >> 16) & 255, c3 = ftot >> 24;
      int T = c0 + c1 + c2 + c3;
      int x = T;
#pragma unroll
      for (int off = 1; off < 64; off <<= 1) {
        int y = __shfl_up(x, off);
        if (l >= off) x += y;
      }
      int waveTotal = __shfl(x, 63);
      int sb = 0;
      if (l == 63) sb = atomicAdd(cursor, waveTotal);
      sb = __shfl(sb, 63);
      int E = sb + x - T;
      if (ok) {
        int4 cv = {c0, c1, c2, c3};
        int4 rv = {E, E + c0, E + c0 + c1, E + c0 + c1 + c2};
        ((int4*)cnt)[wd] = cv;
        ((int4*)row_start)[wd] = rv;
      }
    }
  } else {
    if (w == 0 && ok) {
      unsigned ftot = tot[0][l] + tot[1][l] + tot[2][l] + tot[3][l];
      float4 nv;
      int d0 = ftot & 255, d1 = (ftot >> 8) & 255, d2 = (ftot >> 16) & 255, d3 = (int)(ftot >> 24);
      nv.x = 1.0f / (float)(d0 > 1 ? d0 : 1);
      nv.y = 1.0f / (float)(d1 > 1 ? d1 : 1);
      nv.z = 1.0f / (float)(d2 > 1 ? d2 : 1);
      nv.w = 1.0f / (float)(d3 > 1 ? d3 : 1);
      ((float4*)norm)[wd] = nv;
    }
  }
}

// ---- scatter: stateless, 4 edges/thread, plain stores (verified R5 optimum) ----
__global__ __launch_bounds__(256) void scat_kernel(const int* __restrict__ src,
                                                   const int* __restrict__ dst,
                                                   const int* __restrict__ row_start,
                                                   const unsigned char* __restrict__ delta8,
                                                   const unsigned char* __restrict__ rank8,
                                                   int* __restrict__ eidx) {
  int gt = blockIdx.x * 256 + threadIdx.x;
  int e = gt * 4;
  if (e >= N_EDGES) return;
  int4 d4 = *(const int4*)(dst + e);
  int4 s4 = *(const int4*)(src + e);
  unsigned rr = *(const unsigned*)(rank8 + e);
  int dd[4] = {d4.x, d4.y, d4.z, d4.w};
  int ss[4] = {s4.x, s4.y, s4.z, s4.w};
#pragma unroll
  for (int k = 0; k < 4; ++k) {
    int c = (e + k) / EPC;
    int d = dd[k];
    int pos = row_start[d] + (int)delta8[(size_t)c * N_NODES + d] + (int)((rr >> (8 * k)) & 0xFFu);
    eidx[pos] = ss[k];
  }
}

// ---- agg: uint4 (16B) gathers — 16 lanes/row, 4 rows x 4-deep = 16 rows in
// flight per wave (2x bytes-in-flight, ~half the instructions per byte vs the
// uint2 version). Avg degree 16 exactly fills one unrolled iteration.
__global__ __launch_bounds__(256) void agg_kernel(const unsigned short* __restrict__ h,
                                                  const int* __restrict__ row_start,
                                                  const int* __restrict__ cnt,
                                                  const int* __restrict__ eidx,
                                                  const float* __restrict__ norm,
                                                  const float* __restrict__ bias,
                                                  float* __restrict__ out) {
  int w = threadIdx.x >> 6, l = threadIdx.x & 63;
  int d = blockIdx.x * 4 + w;  // grid 12500 -> exactly 50000
  int rs = row_start[d], re = rs + cnt[d];
  const uint4* __restrict__ hu4 = (const uint4*)h;  // 16 uint4 per 256B row
  int rowsel = l >> 4;  // 0..3: which of 4 rows in flight
  int cp = l & 15;      // uint4 index within row -> cols 8*cp .. 8*cp+7
  float a0 = 0.f, a1 = 0.f, a2 = 0.f, a3 = 0.f, a4 = 0.f, a5 = 0.f, a6 = 0.f, a7 = 0.f;

  auto acc8 = [&](uint4 v, float nm) {
    a0 = fmaf(bflo(v.x), nm, a0); a1 = fmaf(bfhi(v.x), nm, a1);
    a2 = fmaf(bflo(v.y), nm, a2); a3 = fmaf(bfhi(v.y), nm, a3);
    a4 = fmaf(bflo(v.z), nm, a4); a5 = fmaf(bfhi(v.z), nm, a5);
    a6 = fmaf(bflo(v.w), nm, a6); a7 = fmaf(bfhi(v.w), nm, a7);
  };

  for (int bse = rs; bse < re; bse += 64) {
    int n = re - bse; if (n > 64) n = 64;
    int e = (l < n) ? eidx[bse + l] : 0;
    int quarter = (n + 3) >> 2;  // ceil(n/4) row-group steps
    int j = 0;
    for (; j + 4 <= quarter; j += 4) {  // 16 rows per iteration, 4 x 16B gathers/lane
      int i0 = 4 * j + rowsel;
      int s0 = __shfl(e, i0);
      int s1 = __shfl(e, i0 + 4);
      int s2 = __shfl(e, i0 + 8);
      int s3 = __shfl(e, i0 + 12);
      uint4 v0 = hu4[(size_t)s0 * 16 + cp];
      uint4 v1 = hu4[(size_t)s1 * 16 + cp];
      uint4 v2 = hu4[(size_t)s2 * 16 + cp];
      uint4 v3 = hu4[(size_t)s3 * 16 + cp];
      float nm0 = norm[s0], nm1 = norm[s1], nm2 = norm[s2], nm3 = norm[s3];
      if (i0 >= n) v0 = (uint4){0u, 0u, 0u, 0u};
      if (i0 + 4 >= n) v1 = (uint4){0u, 0u, 0u, 0u};
      if (i0 + 8 >= n) v2 = (uint4){0u, 0u, 0u, 0u};
      if (i0 + 12 >= n) v3 = (uint4){0u, 0u, 0u, 0u};
      acc8(v0, nm0);
      acc8(v1, nm1);
      acc8(v2, nm2);
      acc8(v3, nm3);
    }
    for (; j < quarter; ++j) {
      int i0 = 4 * j + rowsel;
      int s0 = __shfl(e, i0);
      uint4 v0 = hu4[(size_t)s0 * 16 + cp];
      float nm0 = norm[s0];
      if (i0 >= n) v0 = (uint4){0u, 0u, 0u, 0u};
      acc8(v0, nm0);
    }
  }
  // sum the 4 rowsel groups: lanes {cp, cp+16, cp+32, cp+48}
  a0 += __shfl_xor(a0, 16); a1 += __shfl_xor(a1, 16);
  a2 += __shfl_xor(a2, 16); a3 += __shfl_xor(a3, 16);
  a4 += __shfl_xor(a4, 16); a5 += __shfl_xor(a5, 16);
  a6 += __shfl_xor(a6, 16); a7 += __shfl_xor(a7, 16);
  a0 += __shfl_xor(a0, 32); a1 += __shfl_xor(a1, 32);
  a2 += __shfl_xor(a2, 32); a3 += __shfl_xor(a3, 32);
  a4 += __shfl_xor(a4, 32); a5 += __shfl_xor(a5, 32);
  a6 += __shfl_xor(a6, 32); a7 += __shfl_xor(a7, 32);
  if (rowsel == 0) {
    float4 b0 = ((const float4*)bias)[2 * cp];
    float4 b1 = ((const float4*)bias)[2 * cp + 1];
    float4 o0, o1;
    o0.x = a0 + b0.x; o0.y = a1 + b0.y; o0.z = a2 + b0.z; o0.w = a3 + b0.w;
    o1.x = a4 + b1.x; o1.y = a5 + b1.y; o1.z = a6 + b1.z; o1.w = a7 + b1.w;
    float4* op = (float4*)(out + (size_t)d * OUT_F + 8 * cp);
    op[0] = o0;
    op[1] = o1;
  }
}

extern "C" void kernel_launch(void* const* d_in, const int* in_sizes, int n_in,
                              void* d_out, int out_size, void* d_ws, size_t ws_size,
                              hipStream_t stream) {
  const float* feat = (const float*)d_in[0];
  const float* weight = (const float*)d_in[1];
  const float* bias = (const float*)d_in[2];
  const int* src = (const int*)d_in[3];
  const int* dst = (const int*)d_in[4];
  float* out = (float*)d_out;

  char* ws = (char*)d_ws;
  size_t off = 0;
  auto alloc = [&](size_t bytes) -> void* {
    void* p = ws + off;
    off += (bytes + 511) & ~(size_t)511;
    return p;
  };
  int* cursor = (int*)alloc(4);
  int* cnt = (int*)alloc(N_NODES * 4);
  int* row_start = (int*)alloc(N_NODES * 4);
  float* norm = (float*)alloc(N_NODES * 4);
  int* eidx = (int*)alloc(N_EDGES * 4);
  unsigned short* h = (unsigned short*)alloc((size_t)N_NODES * OUT_F * 2);
  unsigned char* pdst8 = (unsigned char*)alloc((size_t)CHUNKS * N_NODES);
  unsigned char* psrc8 = (unsigned char*)alloc((size_t)CHUNKS * N_NODES);
  unsigned char* delta8 = (unsigned char*)alloc((size_t)CHUNKS * N_NODES);
  unsigned char* rank8 = (unsigned char*)alloc((size_t)N_EDGES);
  (void)off; (void)ws_size; (void)in_sizes; (void)n_in; (void)out_size;

  hipLaunchKernelGGL(fused1_kernel, dim3(HIST_BLOCKS + GEMMF_BLOCKS), dim3(512), 0, stream,
                     src, dst, pdst8, psrc8, rank8, weight, feat, h, cursor);
  hipLaunchKernelGGL(reduceoff_kernel, dim3(RGB, 2), dim3(256), 0, stream,
                     pdst8, psrc8, delta8, cnt, row_start, cursor, norm);
  hipLaunchKernelGGL(scat_kernel, dim3(SCAT_BLOCKS), dim3(256), 0, stream,
                     src, dst, row_start, delta8, rank8, eidx);
  hipLaunchKernelGGL(agg_kernel, dim3(N_NODES / 4), dim3(256), 0, stream,
                     h, row_start, cnt, eidx, norm, bias, out);
}